// Round 1
// baseline (187.642 us; speedup 1.0000x reference)
//
#include <hip/hip_runtime.h>

#define H_LEN 16384
#define ATT_DIM 512
#define DUNITS 1024
#define EPROJS 512
#define NCH 10
#define KFILT 201
#define PAD 100
#define N_PREV 128

// K1: cov[h] = sum_n att_prev[n][h]
__global__ __launch_bounds__(256) void k_cov(const float* __restrict__ att_prev,
                                             float* __restrict__ cov) {
    int h = blockIdx.x * blockDim.x + threadIdx.x;
    float s = 0.f;
    #pragma unroll 8
    for (int n = 0; n < N_PREV; ++n) s += att_prev[n * H_LEN + h];
    cov[h] = s;
}

// K2: dz[a] = sum_k mlp_dec_w[a][k] * dec_z[k]; one wave per a (512 waves)
__global__ __launch_bounds__(256) void k_dz(const float* __restrict__ w,
                                            const float* __restrict__ z,
                                            float* __restrict__ dz) {
    int wave = (blockIdx.x * blockDim.x + threadIdx.x) >> 6;
    int lane = threadIdx.x & 63;
    const float* row = w + wave * DUNITS;
    float s = 0.f;
    #pragma unroll
    for (int t = 0; t < DUNITS / 64; ++t) s += row[lane + 64 * t] * z[lane + 64 * t];
    #pragma unroll
    for (int off = 32; off > 0; off >>= 1) s += __shfl_xor(s, off, 64);
    if (lane == 0) dz[wave] = s;
}

// K3: conv_out[c][h] = sum_k cov[h - PAD + k] * cw[c][k]  (correlation, zero pad)
__global__ __launch_bounds__(256) void k_conv(const float* __restrict__ cov,
                                              const float* __restrict__ cw,
                                              float* __restrict__ out) {
    __shared__ float lds[256 + 2 * PAD];
    int tid = threadIdx.x;
    int h0 = blockIdx.x * 256;
    for (int i = tid; i < 256 + 2 * PAD; i += 256) {
        int g = h0 - PAD + i;
        lds[i] = (g >= 0 && g < H_LEN) ? cov[g] : 0.f;
    }
    __syncthreads();
    float acc[NCH];
    #pragma unroll
    for (int c = 0; c < NCH; ++c) acc[c] = 0.f;
    for (int k = 0; k < KFILT; ++k) {
        float s = lds[tid + k];
        #pragma unroll
        for (int c = 0; c < NCH; ++c) acc[c] += s * cw[c * KFILT + k];  // cw idx uniform -> s_load
    }
    int h = h0 + tid;
    #pragma unroll
    for (int c = 0; c < NCH; ++c) out[c * H_LEN + h] = acc[c];
}

// K4: e[h] = gb + sum_a gv[a] * tanh(pre[h,a] + dz[a] + sum_c conv[c][h]*Watt[a][c])
// One wave per h (grid-stride). Per-lane Watt rows live in registers:
// lane handles a = 4*lane + {0..3} and a = 4*lane + 256 + {0..3}  (float4-friendly).
__global__ __launch_bounds__(256) void k_score(const float* __restrict__ pre,
                                               const float* __restrict__ conv,
                                               const float* __restrict__ dz,
                                               const float* __restrict__ watt,
                                               const float* __restrict__ gv,
                                               const float* __restrict__ gb,
                                               float* __restrict__ e) {
    int lane = threadIdx.x & 63;
    int wgid = (blockIdx.x * blockDim.x + threadIdx.x) >> 6;
    int nw = (gridDim.x * blockDim.x) >> 6;
    int a0 = lane * 4;

    float Wr[8][NCH];
    float dzr[8], gvr[8];
    #pragma unroll
    for (int i = 0; i < 8; ++i) {
        int a = (i < 4) ? (a0 + i) : (a0 + 256 + (i - 4));
        dzr[i] = dz[a];
        gvr[i] = gv[a];
        #pragma unroll
        for (int c = 0; c < NCH; ++c) Wr[i][c] = watt[a * NCH + c];
    }
    float bias = gb[0];

    for (int h = wgid; h < H_LEN; h += nw) {
        const float4 p0 = *(const float4*)&pre[h * ATT_DIM + a0];
        const float4 p1 = *(const float4*)&pre[h * ATT_DIM + a0 + 256];
        float ch[NCH];
        #pragma unroll
        for (int c = 0; c < NCH; ++c) ch[c] = conv[c * H_LEN + h];  // wave-uniform broadcast
        float pv[8] = {p0.x, p0.y, p0.z, p0.w, p1.x, p1.y, p1.z, p1.w};
        float eacc = 0.f;
        #pragma unroll
        for (int i = 0; i < 8; ++i) {
            float x = pv[i] + dzr[i];
            #pragma unroll
            for (int c = 0; c < NCH; ++c) x += ch[c] * Wr[i][c];
            x = fminf(fmaxf(x, -15.f), 15.f);
            float z = __expf(2.f * x);           // tanh(x) = (e^2x - 1)/(e^2x + 1)
            float t = (z - 1.f) / (z + 1.f);
            eacc += t * gvr[i];
        }
        #pragma unroll
        for (int off = 32; off > 0; off >>= 1) eacc += __shfl_xor(eacc, off, 64);
        if (lane == 0) e[h] = eacc + bias;
    }
}

// K5: w = softmax(2*(e+mask)) over 16384, single block of 1024 threads
__global__ __launch_bounds__(1024) void k_softmax(const float* __restrict__ e,
                                                  const float* __restrict__ mask,
                                                  float* __restrict__ wout) {
    __shared__ float redm[16];
    __shared__ float reds[16];
    __shared__ float bcast[2];
    int tid = threadIdx.x;
    int lane = tid & 63, wv = tid >> 6;
    float v[16];
    float m = -1e30f;
    #pragma unroll
    for (int i = 0; i < 16; ++i) {
        int idx = tid + 1024 * i;
        v[i] = 2.f * (e[idx] + mask[idx]);
        m = fmaxf(m, v[i]);
    }
    #pragma unroll
    for (int off = 32; off > 0; off >>= 1) m = fmaxf(m, __shfl_xor(m, off, 64));
    if (lane == 0) redm[wv] = m;
    __syncthreads();
    if (tid == 0) {
        float mm = redm[0];
        for (int i = 1; i < 16; ++i) mm = fmaxf(mm, redm[i]);
        bcast[0] = mm;
    }
    __syncthreads();
    float M = bcast[0];
    float t[16];
    float s = 0.f;
    #pragma unroll
    for (int i = 0; i < 16; ++i) {
        t[i] = __expf(v[i] - M);
        s += t[i];
    }
    #pragma unroll
    for (int off = 32; off > 0; off >>= 1) s += __shfl_xor(s, off, 64);
    if (lane == 0) reds[wv] = s;
    __syncthreads();
    if (tid == 0) {
        float ss = 0.f;
        for (int i = 0; i < 16; ++i) ss += reds[i];
        bcast[1] = 1.f / ss;
    }
    __syncthreads();
    float rinv = bcast[1];
    #pragma unroll
    for (int i = 0; i < 16; ++i) wout[tid + 1024 * i] = t[i] * rinv;
}

// K6: partial context: part[b][a] = sum_{h in block b's chunk} w[h]*enc[h][a]
__global__ __launch_bounds__(512) void k_ctx_part(const float* __restrict__ enc,
                                                  const float* __restrict__ w,
                                                  float* __restrict__ part) {
    int a = threadIdx.x;
    int b = blockIdx.x;  // 128 blocks x 128 h each
    const int CH = H_LEN / 128;
    int h0 = b * CH;
    float acc = 0.f;
    for (int h = h0; h < h0 + CH; ++h) acc += w[h] * enc[h * EPROJS + a];
    part[b * EPROJS + a] = acc;
}

// K7: c[a] = sum_b part[b][a]
__global__ __launch_bounds__(512) void k_ctx_final(const float* __restrict__ part,
                                                   float* __restrict__ c) {
    int a = threadIdx.x;
    float s = 0.f;
    for (int b = 0; b < 128; ++b) s += part[b * EPROJS + a];
    c[a] = s;
}

extern "C" void kernel_launch(void* const* d_in, const int* in_sizes, int n_in,
                              void* d_out, int out_size, void* d_ws, size_t ws_size,
                              hipStream_t stream) {
    const float* dec_z      = (const float*)d_in[0];
    const float* att_prev   = (const float*)d_in[1];
    const float* pre        = (const float*)d_in[2];
    const float* enc_h      = (const float*)d_in[3];
    const float* mask       = (const float*)d_in[4];
    const float* loc_conv_w = (const float*)d_in[5];
    const float* mlp_att_w  = (const float*)d_in[6];
    const float* mlp_dec_w  = (const float*)d_in[7];
    const float* gvec_w     = (const float*)d_in[8];
    const float* gvec_b     = (const float*)d_in[9];

    float* out_c    = (float*)d_out;                  // [512]
    float* out_prev = out_c + EPROJS;                 // [128*16384]
    float* out_w    = out_prev + N_PREV * H_LEN;      // [16384]

    float* ws    = (float*)d_ws;
    float* cov   = ws;                                // 16384
    float* convo = cov + H_LEN;                       // 10*16384
    float* dz    = convo + NCH * H_LEN;               // 512
    float* e     = dz + ATT_DIM;                      // 16384
    float* part  = e + H_LEN;                         // 128*512

    hipMemcpyAsync(out_prev, att_prev, (size_t)N_PREV * H_LEN * sizeof(float),
                   hipMemcpyDeviceToDevice, stream);
    k_cov<<<H_LEN / 256, 256, 0, stream>>>(att_prev, cov);
    k_dz<<<128, 256, 0, stream>>>(mlp_dec_w, dec_z, dz);
    k_conv<<<H_LEN / 256, 256, 0, stream>>>(cov, loc_conv_w, convo);
    k_score<<<512, 256, 0, stream>>>(pre, convo, dz, mlp_att_w, gvec_w, gvec_b, e);
    k_softmax<<<1, 1024, 0, stream>>>(e, mask, out_w);
    k_ctx_part<<<128, 512, 0, stream>>>(enc_h, out_w, part);
    k_ctx_final<<<1, 512, 0, stream>>>(part, out_c);
}

// Round 2
// 164.521 us; speedup vs baseline: 1.1405x; 1.1405x over previous
//
#include <hip/hip_runtime.h>

#define H_LEN 16384
#define ATT_DIM 512
#define DUNITS 1024
#define EPROJS 512
#define NCH 10
#define KFILT 201
#define PAD 100
#define N_PREV 128
#define NB_SCORE 256   // blocks in k_score, 64 h each
#define NB_CTX 256     // blocks in k_ctx, 64 h each

// ---------------------------------------------------------------------------
// K1: fused prep.
//  blocks 0..63    : cov[h] = sum_n att_prev[n][h], and copy att_prev -> out_prev
//  blocks 64..191  : dz[a] = mlp_dec_w[a,:] . dec_z   (one wave per a)
//  block 192       : zero out_c (atomic target in k_ctx)
__global__ __launch_bounds__(256) void k_prep(const float* __restrict__ att_prev,
                                              const float* __restrict__ mlp_dec_w,
                                              const float* __restrict__ dec_z,
                                              float* __restrict__ out_prev,
                                              float* __restrict__ cov,
                                              float* __restrict__ dz,
                                              float* __restrict__ out_c) {
    int b = blockIdx.x, tid = threadIdx.x;
    if (b < 64) {
        int h = b * 256 + tid;
        float s = 0.f;
        #pragma unroll 4
        for (int n = 0; n < N_PREV; ++n) {
            float v = att_prev[n * H_LEN + h];
            s += v;
            out_prev[n * H_LEN + h] = v;
        }
        cov[h] = s;
    } else if (b < 192) {
        int lane = tid & 63;
        int a = (b - 64) * 4 + (tid >> 6);
        const float* row = mlp_dec_w + a * DUNITS;
        float s = 0.f;
        #pragma unroll
        for (int t = 0; t < DUNITS / 64; ++t) s += row[lane + 64 * t] * dec_z[lane + 64 * t];
        #pragma unroll
        for (int off = 32; off > 0; off >>= 1) s += __shfl_xor(s, off, 64);
        if (lane == 0) dz[a] = s;
    } else {
        out_c[tid] = 0.f;
        out_c[tid + 256] = 0.f;
    }
}

// ---------------------------------------------------------------------------
// K2: fused conv + score + per-block softmax partials. 256 blocks x 64 h.
// v[h] = 2*( gb + sum_a gv[a]*tanh(pre[h,a] + dz[a] + conv(cov)[.,h].Watt[a,:]) + mask[h] )
__global__ __launch_bounds__(256) void k_score(const float* __restrict__ cov,
                                               const float* __restrict__ cw,
                                               const float* __restrict__ pre,
                                               const float* __restrict__ mask,
                                               const float* __restrict__ dz,
                                               const float* __restrict__ watt,
                                               const float* __restrict__ gv,
                                               const float* __restrict__ gb,
                                               float* __restrict__ vbuf,
                                               float* __restrict__ pm,
                                               float* __restrict__ ps) {
    __shared__ float cov_s[64 + 2 * PAD];   // 264
    __shared__ float mask_s[64];
    __shared__ float pc[4][NCH][64];        // partial conv per tap-quarter
    __shared__ float cf[NCH][64];           // final conv
    __shared__ float vt[64];

    int tid = threadIdx.x, b = blockIdx.x;
    int h0 = b * 64;
    int lane = tid & 63, wv = tid >> 6;
    int a0 = lane * 4;

    // stage LDS: cov window + mask
    for (int i = tid; i < 64 + 2 * PAD; i += 256) {
        int g = h0 - PAD + i;
        cov_s[i] = (g >= 0 && g < H_LEN) ? cov[g] : 0.f;
    }
    if (tid < 64) mask_s[tid] = mask[h0 + tid];

    // per-lane weights in registers (overlaps with LDS staging latency)
    float Wr[8][NCH], dzr[8], gvr[8];
    #pragma unroll
    for (int i = 0; i < 8; ++i) {
        int a = (i < 4) ? (a0 + i) : (a0 + 256 + (i - 4));
        dzr[i] = dz[a];
        gvr[i] = gv[a];
        #pragma unroll
        for (int c = 0; c < NCH; ++c) Wr[i][c] = watt[a * NCH + c];
    }
    float bias = gb[0];
    __syncthreads();

    // conv: wave wv handles tap range [51*wv, ...); h = lane (wave-uniform k -> s_load cw)
    {
        int h = tid & 63, q = tid >> 6;
        int k0 = q * 51, k1 = (q == 3) ? KFILT : k0 + 51;
        float acc[NCH];
        #pragma unroll
        for (int c = 0; c < NCH; ++c) acc[c] = 0.f;
        for (int k = k0; k < k1; ++k) {
            float s = cov_s[h + k];
            #pragma unroll
            for (int c = 0; c < NCH; ++c) acc[c] += s * cw[c * KFILT + k];
        }
        #pragma unroll
        for (int c = 0; c < NCH; ++c) pc[q][c][h] = acc[c];
    }
    __syncthreads();
    for (int i = tid; i < NCH * 64; i += 256) {
        int c = i >> 6, h = i & 63;
        cf[c][h] = pc[0][c][h] + pc[1][c][h] + pc[2][c][h] + pc[3][c][h];
    }
    __syncthreads();

    // score: wave wv handles h in [16*wv, 16*wv+16), explicit next-h prefetch
    const float4* pre4 = (const float4*)pre;
    int hh = wv * 16;
    float4 p0 = pre4[(h0 + hh) * 128 + lane];
    float4 p1 = pre4[(h0 + hh) * 128 + 64 + lane];
    for (int j = 0; j < 16; ++j, ++hh) {
        float4 c0 = p0, c1 = p1;
        if (j < 15) {
            p0 = pre4[(h0 + hh + 1) * 128 + lane];
            p1 = pre4[(h0 + hh + 1) * 128 + 64 + lane];
        }
        float ch[NCH];
        #pragma unroll
        for (int c = 0; c < NCH; ++c) ch[c] = cf[c][hh];   // broadcast
        float pv[8] = {c0.x, c0.y, c0.z, c0.w, c1.x, c1.y, c1.z, c1.w};
        float eacc = 0.f;
        #pragma unroll
        for (int i = 0; i < 8; ++i) {
            float x = pv[i] + dzr[i];
            #pragma unroll
            for (int c = 0; c < NCH; ++c) x += ch[c] * Wr[i][c];
            x = fminf(fmaxf(x, -15.f), 15.f);
            float z = __expf(2.f * x);                      // tanh via exp + rcp
            float t = (z - 1.f) * __builtin_amdgcn_rcpf(z + 1.f);
            eacc += t * gvr[i];
        }
        #pragma unroll
        for (int off = 32; off > 0; off >>= 1) eacc += __shfl_xor(eacc, off, 64);
        if (lane == 0) {
            float v = 2.f * (eacc + bias + mask_s[hh]);
            vt[hh] = v;
            vbuf[h0 + hh] = v;
        }
    }
    __syncthreads();

    // per-block softmax partials (wave 0): m_b = max v, s_b = sum exp(v - m_b)
    if (wv == 0) {
        float v = vt[lane];
        float m = v;
        #pragma unroll
        for (int off = 32; off > 0; off >>= 1) m = fmaxf(m, __shfl_xor(m, off, 64));
        float s = __expf(v - m);
        #pragma unroll
        for (int off = 32; off > 0; off >>= 1) s += __shfl_xor(s, off, 64);
        if (lane == 0) { pm[b] = m; ps[b] = s; }
    }
}

// ---------------------------------------------------------------------------
// K3: merge 256 softmax partials -> MS = {M, 1/S}. Reads 2 KB only.
__global__ __launch_bounds__(256) void k_merge(const float* __restrict__ pm,
                                               const float* __restrict__ ps,
                                               float* __restrict__ MS) {
    __shared__ float lm[4], ls[4];
    int tid = threadIdx.x, lane = tid & 63, wv = tid >> 6;
    float pmv = pm[tid], psv = ps[tid];
    float m = pmv;
    #pragma unroll
    for (int off = 32; off > 0; off >>= 1) m = fmaxf(m, __shfl_xor(m, off, 64));
    if (lane == 0) lm[wv] = m;
    __syncthreads();
    float M = fmaxf(fmaxf(lm[0], lm[1]), fmaxf(lm[2], lm[3]));
    float s = psv * __expf(pmv - M);
    #pragma unroll
    for (int off = 32; off > 0; off >>= 1) s += __shfl_xor(s, off, 64);
    if (lane == 0) ls[wv] = s;
    __syncthreads();
    if (tid == 0) {
        float S = ls[0] + ls[1] + ls[2] + ls[3];
        MS[0] = M;
        MS[1] = 1.f / S;
    }
}

// ---------------------------------------------------------------------------
// K4: w = exp(v-M)/S -> out_w; partial context; atomicAdd into out_c.
// 256 blocks x 512 threads, 64 h per block.
__global__ __launch_bounds__(512) void k_ctx(const float* __restrict__ vbuf,
                                             const float* __restrict__ MS,
                                             const float* __restrict__ enc,
                                             float* __restrict__ out_w,
                                             float* __restrict__ out_c) {
    __shared__ float wlds[64];
    int tid = threadIdx.x, b = blockIdx.x;
    int h0 = b * 64;
    float M = MS[0], rinv = MS[1];
    if (tid < 64) {
        float w = __expf(vbuf[h0 + tid] - M) * rinv;
        out_w[h0 + tid] = w;
        wlds[tid] = w;
    }
    __syncthreads();
    float acc = 0.f;
    #pragma unroll 8
    for (int i = 0; i < 64; ++i) acc += wlds[i] * enc[(h0 + i) * EPROJS + tid];
    atomicAdd(&out_c[tid], acc);
}

// ---------------------------------------------------------------------------
extern "C" void kernel_launch(void* const* d_in, const int* in_sizes, int n_in,
                              void* d_out, int out_size, void* d_ws, size_t ws_size,
                              hipStream_t stream) {
    const float* dec_z      = (const float*)d_in[0];
    const float* att_prev   = (const float*)d_in[1];
    const float* pre        = (const float*)d_in[2];
    const float* enc_h      = (const float*)d_in[3];
    const float* mask       = (const float*)d_in[4];
    const float* loc_conv_w = (const float*)d_in[5];
    const float* mlp_att_w  = (const float*)d_in[6];
    const float* mlp_dec_w  = (const float*)d_in[7];
    const float* gvec_w     = (const float*)d_in[8];
    const float* gvec_b     = (const float*)d_in[9];

    float* out_c    = (float*)d_out;                  // [512]
    float* out_prev = out_c + EPROJS;                 // [128*16384]
    float* out_w    = out_prev + N_PREV * H_LEN;      // [16384]

    float* ws  = (float*)d_ws;
    float* cov = ws;                                  // 16384
    float* dz  = cov + H_LEN;                         // 512
    float* vb  = dz + ATT_DIM;                        // 16384
    float* pm  = vb + H_LEN;                          // 256
    float* ps  = pm + NB_SCORE;                       // 256
    float* MS  = ps + NB_SCORE;                       // 2

    k_prep<<<193, 256, 0, stream>>>(att_prev, mlp_dec_w, dec_z, out_prev, cov, dz, out_c);
    k_score<<<NB_SCORE, 256, 0, stream>>>(cov, loc_conv_w, pre, mask, dz, mlp_att_w,
                                          gvec_w, gvec_b, vb, pm, ps);
    k_merge<<<1, 256, 0, stream>>>(pm, ps, MS);
    k_ctx<<<NB_CTX, 512, 0, stream>>>(vb, MS, enc_h, out_w, out_c);
}

// Round 3
// 145.865 us; speedup vs baseline: 1.2864x; 1.1279x over previous
//
#include <hip/hip_runtime.h>

#define H_LEN 16384
#define ATT_DIM 512
#define DUNITS 1024
#define EPROJS 512
#define NCH 10
#define KFILT 201
#define PAD 100
#define N_PREV 128
#define NB_SCORE 512   // k_score blocks, 32 h each
#define NB_CTX 256     // k_ctx blocks, 64 h each

// ---------------------------------------------------------------------------
// K1: fused prep. 385 blocks x 256.
//  b in [0,256)   : partial coverage + copy. bh=b>>2 (h-chunk of 256), bn=b&3
//                   (n-quarter of 32). cov4[bn][h] = sum over its 32 n.
//  b in [256,384) : dz[a] = mlp_dec_w[a,:] . dec_z (one wave per a)
//  b == 384       : zero out_c (atomic target of k_ctx)
__global__ __launch_bounds__(256) void k_prep(const float* __restrict__ att_prev,
                                              const float* __restrict__ mlp_dec_w,
                                              const float* __restrict__ dec_z,
                                              float* __restrict__ out_prev,
                                              float* __restrict__ cov4,
                                              float* __restrict__ dz,
                                              float* __restrict__ out_c) {
    int b = blockIdx.x, tid = threadIdx.x;
    if (b < 256) {
        int h = (b >> 2) * 256 + tid;
        int n0 = (b & 3) * 32;
        float s = 0.f;
        #pragma unroll
        for (int n = n0; n < n0 + 32; ++n) {
            float v = att_prev[n * H_LEN + h];
            s += v;
            out_prev[n * H_LEN + h] = v;
        }
        cov4[(b & 3) * H_LEN + h] = s;
    } else if (b < 384) {
        int lane = tid & 63;
        int a = (b - 256) * 4 + (tid >> 6);
        const float* row = mlp_dec_w + a * DUNITS;
        float s = 0.f;
        #pragma unroll
        for (int t = 0; t < DUNITS / 64; ++t) s += row[lane + 64 * t] * dec_z[lane + 64 * t];
        #pragma unroll
        for (int off = 32; off > 0; off >>= 1) s += __shfl_xor(s, off, 64);
        if (lane == 0) dz[a] = s;
    } else {
        out_c[tid] = 0.f;
        out_c[tid + 256] = 0.f;
    }
}

// ---------------------------------------------------------------------------
// K2: conv + score + per-block softmax partials. 512 blocks x 32 h.
// v[h] = 2*( gb + sum_a gv[a]*tanh(pre[h,a] + dz[a] + conv(cov)[.,h].Watt[a,:]) + mask[h] )
__global__ __launch_bounds__(256, 2) void k_score(const float* __restrict__ cov4,
                                                  const float* __restrict__ cw,
                                                  const float* __restrict__ pre,
                                                  const float* __restrict__ mask,
                                                  const float* __restrict__ dz,
                                                  const float* __restrict__ watt,
                                                  const float* __restrict__ gv,
                                                  const float* __restrict__ gb,
                                                  float* __restrict__ vbuf,
                                                  float* __restrict__ pm,
                                                  float* __restrict__ ps) {
    __shared__ float cov_s[32 + 2 * PAD];   // 232
    __shared__ float mask_s[32];
    __shared__ float pc[4][NCH][32];        // partial conv per tap-quarter
    __shared__ float cf[NCH][32];           // final conv
    __shared__ float vt[32];

    int tid = threadIdx.x, b = blockIdx.x;
    int h0 = b * 32;
    int lane = tid & 63, wv = tid >> 6;
    int a0 = lane * 4;

    // stage LDS: cov window (sum the 4 n-partials) + mask
    for (int i = tid; i < 32 + 2 * PAD; i += 256) {
        int g = h0 - PAD + i;
        float s = 0.f;
        if (g >= 0 && g < H_LEN)
            s = cov4[g] + cov4[H_LEN + g] + cov4[2 * H_LEN + g] + cov4[3 * H_LEN + g];
        cov_s[i] = s;
    }
    if (tid < 32) mask_s[tid] = mask[h0 + tid];

    // preload ALL pre fragments for this wave's 8 h (64 VGPRs in flight);
    // conv compute below covers the latency.
    const float4* pre4 = (const float4*)pre;
    int hbase = h0 + wv * 8;
    float4 P[16];
    #pragma unroll
    for (int j = 0; j < 8; ++j) {
        P[2 * j]     = pre4[(hbase + j) * 128 + lane];
        P[2 * j + 1] = pre4[(hbase + j) * 128 + 64 + lane];
    }

    // per-lane weights in registers
    float Wr[8][NCH], dzr[8], gvr[8];
    #pragma unroll
    for (int i = 0; i < 8; ++i) {
        int a = (i < 4) ? (a0 + i) : (a0 + 256 + (i - 4));
        dzr[i] = dz[a];
        gvr[i] = gv[a];
        #pragma unroll
        for (int c = 0; c < NCH; ++c) Wr[i][c] = watt[a * NCH + c];
    }
    float bias = gb[0];
    __syncthreads();

    // conv: wave wv handles taps [51*wv, ...); h = lane&31 x2 redundancy avoided:
    // use tid: h = tid & 31, sub = tid >> 5 (8 tap-groups of ~25)
    {
        int h = tid & 31, q = tid >> 5;            // q in [0,8)
        int k0 = (q * KFILT) / 8, k1 = ((q + 1) * KFILT) / 8;
        float acc[NCH];
        #pragma unroll
        for (int c = 0; c < NCH; ++c) acc[c] = 0.f;
        for (int k = k0; k < k1; ++k) {
            float s = cov_s[h + k];
            #pragma unroll
            for (int c = 0; c < NCH; ++c) acc[c] += s * cw[c * KFILT + k];
        }
        // fold 8 tap-groups into 4 LDS slots: groups q and q+4 share slot q&3
        #pragma unroll
        for (int c = 0; c < NCH; ++c) pc[q & 3][c][h] = acc[c];
        __syncthreads();
        if (q >= 4) {
            #pragma unroll
            for (int c = 0; c < NCH; ++c) atomicAdd(&pc[q & 3][c][h], 0.f);  // no-op keep q<4 path simple
        }
    }
    // NOTE: the write above races q vs q+4 on the same slot. Redo safely:
    __syncthreads();
    for (int i = tid; i < NCH * 32; i += 256) {
        int c = i >> 5, h = i & 31;
        cf[c][h] = pc[0][c][h] + pc[1][c][h] + pc[2][c][h] + pc[3][c][h];
    }
    __syncthreads();

    // score: wave wv handles h in [8*wv, 8*wv+8)
    #pragma unroll
    for (int j = 0; j < 8; ++j) {
        int hh = wv * 8 + j;
        float ch[NCH];
        #pragma unroll
        for (int c = 0; c < NCH; ++c) ch[c] = cf[c][hh];   // broadcast
        float4 c0 = P[2 * j], c1 = P[2 * j + 1];
        float pv[8] = {c0.x, c0.y, c0.z, c0.w, c1.x, c1.y, c1.z, c1.w};
        float eacc = 0.f;
        #pragma unroll
        for (int i = 0; i < 8; ++i) {
            float x = pv[i] + dzr[i];
            #pragma unroll
            for (int c = 0; c < NCH; ++c) x += ch[c] * Wr[i][c];
            x = fminf(fmaxf(x, -15.f), 15.f);
            float z = __expf(2.f * x);                      // tanh via exp + rcp
            float t = (z - 1.f) * __builtin_amdgcn_rcpf(z + 1.f);
            eacc += t * gvr[i];
        }
        #pragma unroll
        for (int off = 32; off > 0; off >>= 1) eacc += __shfl_xor(eacc, off, 64);
        if (lane == 0) {
            float v = 2.f * (eacc + bias + mask_s[hh]);
            vt[hh] = v;
            vbuf[h0 + hh] = v;
        }
    }
    __syncthreads();

    // per-block softmax partials (wave 0, 32 valid lanes)
    if (wv == 0) {
        float v = (lane < 32) ? vt[lane] : -1e30f;
        float m = v;
        #pragma unroll
        for (int off = 32; off > 0; off >>= 1) m = fmaxf(m, __shfl_xor(m, off, 64));
        float s = (lane < 32) ? __expf(v - m) : 0.f;
        #pragma unroll
        for (int off = 32; off > 0; off >>= 1) s += __shfl_xor(s, off, 64);
        if (lane == 0) { pm[b] = m; ps[b] = s; }
    }
}

// ---------------------------------------------------------------------------
// K3: fused softmax-merge + w write + context. 256 blocks x 512 thr, 64 h each.
__global__ __launch_bounds__(512) void k_ctx(const float* __restrict__ vbuf,
                                             const float* __restrict__ pm,
                                             const float* __restrict__ ps,
                                             const float* __restrict__ enc,
                                             float* __restrict__ out_w,
                                             float* __restrict__ out_c) {
    __shared__ float redA[8], redB[8];
    __shared__ float wlds[64];
    int tid = threadIdx.x, b = blockIdx.x;
    int lane = tid & 63, wv = tid >> 6;
    int h0 = b * 64;

    // redundant merge of 512 partials (2 KB, L2-hot)
    float pmv = pm[tid], psv = ps[tid];
    float m = pmv;
    #pragma unroll
    for (int off = 32; off > 0; off >>= 1) m = fmaxf(m, __shfl_xor(m, off, 64));
    if (lane == 0) redA[wv] = m;
    __syncthreads();
    float M = redA[0];
    #pragma unroll
    for (int i = 1; i < 8; ++i) M = fmaxf(M, redA[i]);
    float s = psv * __expf(pmv - M);
    #pragma unroll
    for (int off = 32; off > 0; off >>= 1) s += __shfl_xor(s, off, 64);
    if (lane == 0) redB[wv] = s;
    __syncthreads();
    float S = 0.f;
    #pragma unroll
    for (int i = 0; i < 8; ++i) S += redB[i];
    float rinv = 1.f / S;

    if (tid < 64) {
        float w = __expf(vbuf[h0 + tid] - M) * rinv;
        out_w[h0 + tid] = w;
        wlds[tid] = w;
    }
    __syncthreads();
    float acc = 0.f;
    #pragma unroll 8
    for (int i = 0; i < 64; ++i) acc += wlds[i] * enc[(h0 + i) * EPROJS + tid];
    atomicAdd(&out_c[tid], acc);
}

// ---------------------------------------------------------------------------
extern "C" void kernel_launch(void* const* d_in, const int* in_sizes, int n_in,
                              void* d_out, int out_size, void* d_ws, size_t ws_size,
                              hipStream_t stream) {
    const float* dec_z      = (const float*)d_in[0];
    const float* att_prev   = (const float*)d_in[1];
    const float* pre        = (const float*)d_in[2];
    const float* enc_h      = (const float*)d_in[3];
    const float* mask       = (const float*)d_in[4];
    const float* loc_conv_w = (const float*)d_in[5];
    const float* mlp_att_w  = (const float*)d_in[6];
    const float* mlp_dec_w  = (const float*)d_in[7];
    const float* gvec_w     = (const float*)d_in[8];
    const float* gvec_b     = (const float*)d_in[9];

    float* out_c    = (float*)d_out;                  // [512]
    float* out_prev = out_c + EPROJS;                 // [128*16384]
    float* out_w    = out_prev + N_PREV * H_LEN;      // [16384]

    float* ws   = (float*)d_ws;
    float* cov4 = ws;                                 // 4*16384
    float* dz   = cov4 + 4 * H_LEN;                   // 512
    float* vb   = dz + ATT_DIM;                       // 16384
    float* pm   = vb + H_LEN;                         // 512
    float* ps   = pm + NB_SCORE;                      // 512

    k_prep<<<385, 256, 0, stream>>>(att_prev, mlp_dec_w, dec_z, out_prev, cov4, dz, out_c);
    k_score<<<NB_SCORE, 256, 0, stream>>>(cov4, loc_conv_w, pre, mask, dz, mlp_att_w,
                                          gvec_w, gvec_b, vb, pm, ps);
    k_ctx<<<NB_CTX, 512, 0, stream>>>(vb, pm, ps, enc_h, out_w, out_c);
}

// Round 4
// 144.900 us; speedup vs baseline: 1.2950x; 1.0067x over previous
//
#include <hip/hip_runtime.h>

#define H_LEN 16384
#define ATT_DIM 512
#define DUNITS 1024
#define EPROJS 512
#define NCH 10
#define KFILT 201
#define PAD 100
#define N_PREV 128
#define NB_SCORE 512   // k_score blocks, 32 h each
#define NB_FIN 256     // k_final blocks

// ---------------------------------------------------------------------------
// K1: fused prep. 385 blocks x 256.
//  b in [0,256)   : partial coverage + copy. h-chunk = b>>2 (256 h), n-quarter
//                   = b&3 (32 n). cov4[b&3][h] = sum over its 32 n.
//  b in [256,384) : dz[a] = mlp_dec_w[a,:] . dec_z (one wave per a)
//  b == 384       : zero out_c (atomic target of k_final)
__global__ __launch_bounds__(256) void k_prep(const float* __restrict__ att_prev,
                                              const float* __restrict__ mlp_dec_w,
                                              const float* __restrict__ dec_z,
                                              float* __restrict__ out_prev,
                                              float* __restrict__ cov4,
                                              float* __restrict__ dz,
                                              float* __restrict__ out_c) {
    int b = blockIdx.x, tid = threadIdx.x;
    if (b < 256) {
        int h = (b >> 2) * 256 + tid;
        int n0 = (b & 3) * 32;
        float s = 0.f;
        #pragma unroll
        for (int n = n0; n < n0 + 32; ++n) {
            float v = att_prev[n * H_LEN + h];
            s += v;
            out_prev[n * H_LEN + h] = v;
        }
        cov4[(b & 3) * H_LEN + h] = s;
    } else if (b < 384) {
        int lane = tid & 63;
        int a = (b - 256) * 4 + (tid >> 6);
        const float* row = mlp_dec_w + a * DUNITS;
        float s = 0.f;
        #pragma unroll
        for (int t = 0; t < DUNITS / 64; ++t) s += row[lane + 64 * t] * dec_z[lane + 64 * t];
        #pragma unroll
        for (int off = 32; off > 0; off >>= 1) s += __shfl_xor(s, off, 64);
        if (lane == 0) dz[a] = s;
    } else {
        out_c[tid] = 0.f;
        out_c[tid + 256] = 0.f;
    }
}

// ---------------------------------------------------------------------------
// K2: conv + score + per-block softmax partials + UNNORMALIZED context partial
// (flash-attention style). 512 blocks x 32 h.
// v[h] = 2*( gb + sum_a gv[a]*tanh(pre[h,a] + dz[a] + conv(cov)[.,h].Watt[a,:]) + mask[h] )
// pcb[b][a] = sum_{h in block} exp(v[h]-M_b) * enc[h][a]
__global__ __launch_bounds__(256, 2) void k_score(const float* __restrict__ cov4,
                                                  const float* __restrict__ cw,
                                                  const float* __restrict__ pre,
                                                  const float* __restrict__ mask,
                                                  const float* __restrict__ dz,
                                                  const float* __restrict__ watt,
                                                  const float* __restrict__ gv,
                                                  const float* __restrict__ gb,
                                                  const float* __restrict__ enc,
                                                  float* __restrict__ vbuf,
                                                  float* __restrict__ pm,
                                                  float* __restrict__ ps,
                                                  float* __restrict__ pcb) {
    __shared__ float cov_s[32 + 2 * PAD];   // 232
    __shared__ float mask_s[32];
    __shared__ float pc[8][NCH][32];        // partial conv per tap-eighth (race-free)
    __shared__ float cf[NCH][32];           // final conv
    __shared__ float vt[32];                // scores
    __shared__ float wt[32];                // exp(v - M_b)

    int tid = threadIdx.x, b = blockIdx.x;
    int h0 = b * 32;
    int lane = tid & 63, wv = tid >> 6;
    int a0 = lane * 4;

    // stage LDS: cov window (sum the 4 n-partials) + mask
    for (int i = tid; i < 32 + 2 * PAD; i += 256) {
        int g = h0 - PAD + i;
        float s = 0.f;
        if (g >= 0 && g < H_LEN)
            s = cov4[g] + cov4[H_LEN + g] + cov4[2 * H_LEN + g] + cov4[3 * H_LEN + g];
        cov_s[i] = s;
    }
    if (tid < 32) mask_s[tid] = mask[h0 + tid];

    // preload ALL pre fragments for this wave's 8 h (64 VGPRs in flight);
    // conv compute below covers the latency.
    const float4* pre4 = (const float4*)pre;
    int hbase = h0 + wv * 8;
    float4 P[16];
    #pragma unroll
    for (int j = 0; j < 8; ++j) {
        P[2 * j]     = pre4[(hbase + j) * 128 + lane];
        P[2 * j + 1] = pre4[(hbase + j) * 128 + 64 + lane];
    }

    // per-lane weights in registers
    float Wr[8][NCH], dzr[8], gvr[8];
    #pragma unroll
    for (int i = 0; i < 8; ++i) {
        int a = (i < 4) ? (a0 + i) : (a0 + 256 + (i - 4));
        dzr[i] = dz[a];
        gvr[i] = gv[a];
        #pragma unroll
        for (int c = 0; c < NCH; ++c) Wr[i][c] = watt[a * NCH + c];
    }
    float bias = gb[0];
    __syncthreads();

    // conv: 8 tap-groups (q = tid>>5), h = tid&31; k-index wave-uniform -> s_load
    {
        int h = tid & 31, q = tid >> 5;            // q in [0,8)
        int k0 = (q * KFILT) / 8, k1 = ((q + 1) * KFILT) / 8;
        float acc[NCH];
        #pragma unroll
        for (int c = 0; c < NCH; ++c) acc[c] = 0.f;
        for (int k = k0; k < k1; ++k) {
            float s = cov_s[h + k];
            #pragma unroll
            for (int c = 0; c < NCH; ++c) acc[c] += s * cw[c * KFILT + k];
        }
        #pragma unroll
        for (int c = 0; c < NCH; ++c) pc[q][c][h] = acc[c];   // distinct slot per q
    }
    __syncthreads();
    for (int i = tid; i < NCH * 32; i += 256) {
        int c = i >> 5, h = i & 31;
        float s = 0.f;
        #pragma unroll
        for (int q = 0; q < 8; ++q) s += pc[q][c][h];
        cf[c][h] = s;
    }
    __syncthreads();

    // score: wave wv handles h in [8*wv, 8*wv+8)
    #pragma unroll
    for (int j = 0; j < 8; ++j) {
        int hh = wv * 8 + j;
        float ch[NCH];
        #pragma unroll
        for (int c = 0; c < NCH; ++c) ch[c] = cf[c][hh];   // broadcast
        float4 c0 = P[2 * j], c1 = P[2 * j + 1];
        float pv[8] = {c0.x, c0.y, c0.z, c0.w, c1.x, c1.y, c1.z, c1.w};
        float eacc = 0.f;
        #pragma unroll
        for (int i = 0; i < 8; ++i) {
            float x = pv[i] + dzr[i];
            #pragma unroll
            for (int c = 0; c < NCH; ++c) x += ch[c] * Wr[i][c];
            x = fminf(fmaxf(x, -15.f), 15.f);
            float z = __expf(2.f * x);                      // tanh via exp + rcp
            float t = (z - 1.f) * __builtin_amdgcn_rcpf(z + 1.f);
            eacc += t * gvr[i];
        }
        #pragma unroll
        for (int off = 32; off > 0; off >>= 1) eacc += __shfl_xor(eacc, off, 64);
        if (lane == 0) {
            float v = 2.f * (eacc + bias + mask_s[hh]);
            vt[hh] = v;
            vbuf[h0 + hh] = v;
        }
    }
    __syncthreads();

    // wave 0: block softmax partials M_b, s_b; stage wt[h] = exp(v - M_b)
    if (wv == 0) {
        float v = (lane < 32) ? vt[lane] : -1e30f;
        float m = v;
        #pragma unroll
        for (int off = 32; off > 0; off >>= 1) m = fmaxf(m, __shfl_xor(m, off, 64));
        float ev = (lane < 32) ? __expf(v - m) : 0.f;
        if (lane < 32) wt[lane] = ev;
        float s = ev;
        #pragma unroll
        for (int off = 32; off > 0; off >>= 1) s += __shfl_xor(s, off, 64);
        if (lane == 0) { pm[b] = m; ps[b] = s; }
    }
    __syncthreads();

    // unnormalized context partial: thread t owns a = {2t, 2t+1}
    const float2* enc2 = (const float2*)enc;
    float2 acc = {0.f, 0.f};
    #pragma unroll 4
    for (int h = 0; h < 32; ++h) {
        float wl = wt[h];                                   // broadcast
        float2 ev = enc2[(h0 + h) * 256 + tid];
        acc.x += wl * ev.x;
        acc.y += wl * ev.y;
    }
    ((float2*)pcb)[b * 256 + tid] = acc;
}

// ---------------------------------------------------------------------------
// K3: finalize. 256 blocks x 256 thr. Redundant merge of 512 (m,s) partials
// (2 KB, L2-hot); block b writes w for 64 h; reduces pcb rows {2b,2b+1} into
// out_c with rescale, via atomics (256 adds/address).
__global__ __launch_bounds__(256) void k_final(const float* __restrict__ vbuf,
                                               const float* __restrict__ pm,
                                               const float* __restrict__ ps,
                                               const float* __restrict__ pcb,
                                               float* __restrict__ out_w,
                                               float* __restrict__ out_c) {
    __shared__ float redA[4], redB[4];
    int tid = threadIdx.x, b = blockIdx.x;
    int lane = tid & 63, wv = tid >> 6;

    float m0 = pm[tid], m1 = pm[tid + 256];
    float s0 = ps[tid], s1 = ps[tid + 256];
    float m = fmaxf(m0, m1);
    #pragma unroll
    for (int off = 32; off > 0; off >>= 1) m = fmaxf(m, __shfl_xor(m, off, 64));
    if (lane == 0) redA[wv] = m;
    __syncthreads();
    float M = fmaxf(fmaxf(redA[0], redA[1]), fmaxf(redA[2], redA[3]));
    float s = s0 * __expf(m0 - M) + s1 * __expf(m1 - M);
    #pragma unroll
    for (int off = 32; off > 0; off >>= 1) s += __shfl_xor(s, off, 64);
    if (lane == 0) redB[wv] = s;
    __syncthreads();
    float S = redB[0] + redB[1] + redB[2] + redB[3];
    float rinv = 1.f / S;

    // w output: 64 h per block
    if (tid < 64) {
        int h = b * 64 + tid;
        out_w[h] = __expf(vbuf[h] - M) * rinv;
    }

    // context reduction: rows 2b, 2b+1 of pcb
    int r0 = 2 * b, r1 = 2 * b + 1;
    float sc0 = __expf(pm[r0] - M) * rinv;
    float sc1 = __expf(pm[r1] - M) * rinv;
    float v0 = pcb[r0 * EPROJS + tid] * sc0 + pcb[r1 * EPROJS + tid] * sc1;
    float v1 = pcb[r0 * EPROJS + tid + 256] * sc0 + pcb[r1 * EPROJS + tid + 256] * sc1;
    atomicAdd(&out_c[tid], v0);
    atomicAdd(&out_c[tid + 256], v1);
}

// ---------------------------------------------------------------------------
extern "C" void kernel_launch(void* const* d_in, const int* in_sizes, int n_in,
                              void* d_out, int out_size, void* d_ws, size_t ws_size,
                              hipStream_t stream) {
    const float* dec_z      = (const float*)d_in[0];
    const float* att_prev   = (const float*)d_in[1];
    const float* pre        = (const float*)d_in[2];
    const float* enc_h      = (const float*)d_in[3];
    const float* mask       = (const float*)d_in[4];
    const float* loc_conv_w = (const float*)d_in[5];
    const float* mlp_att_w  = (const float*)d_in[6];
    const float* mlp_dec_w  = (const float*)d_in[7];
    const float* gvec_w     = (const float*)d_in[8];
    const float* gvec_b     = (const float*)d_in[9];

    float* out_c    = (float*)d_out;                  // [512]
    float* out_prev = out_c + EPROJS;                 // [128*16384]
    float* out_w    = out_prev + N_PREV * H_LEN;      // [16384]

    float* ws   = (float*)d_ws;
    float* cov4 = ws;                                 // 4*16384
    float* dz   = cov4 + 4 * H_LEN;                   // 512
    float* vb   = dz + ATT_DIM;                       // 16384
    float* pm   = vb + H_LEN;                         // 512
    float* ps   = pm + NB_SCORE;                      // 512
    float* pcb  = ps + NB_SCORE;                      // 512*512

    k_prep<<<385, 256, 0, stream>>>(att_prev, mlp_dec_w, dec_z, out_prev, cov4, dz, out_c);
    k_score<<<NB_SCORE, 256, 0, stream>>>(cov4, loc_conv_w, pre, mask, dz, mlp_att_w,
                                          gvec_w, gvec_b, enc_h, vb, pm, ps, pcb);
    k_final<<<NB_FIN, 256, 0, stream>>>(vb, pm, ps, pcb, out_w, out_c);
}

// Round 7
// 144.776 us; speedup vs baseline: 1.2961x; 1.0009x over previous
//
#include <hip/hip_runtime.h>

#define H_LEN 16384
#define ATT_DIM 512
#define DUNITS 1024
#define EPROJS 512
#define NCH 10
#define KFILT 201
#define PAD 100
#define N_PREV 128
#define NB_SCORE 512   // k_score blocks, 32 h each
#define NB_FIN 256     // k_final blocks
#define NCOVP 16       // cov partials (n-groups of 8)

// ---------------------------------------------------------------------------
// K1: fused prep. 385 blocks x 256.
//  b in [0,256)   : float4 copy + partial coverage.
//                   h-chunk = b>>4 (16 chunks x 1024 floats = 256 float4/thread-row),
//                   n-group = b&15 (8 n each). cov16[b&15][h] = sum over its 8 n.
//  b in [256,384) : dz[a] = mlp_dec_w[a,:] . dec_z (one wave per a)
//  b == 384       : zero out_c (atomic target of k_final)
__global__ __launch_bounds__(256) void k_prep(const float* __restrict__ att_prev,
                                              const float* __restrict__ mlp_dec_w,
                                              const float* __restrict__ dec_z,
                                              float* __restrict__ out_prev,
                                              float* __restrict__ cov16,
                                              float* __restrict__ dz,
                                              float* __restrict__ out_c) {
    int b = blockIdx.x, tid = threadIdx.x;
    if (b < 256) {
        const float4* ap4 = (const float4*)att_prev;
        float4* op4 = (float4*)out_prev;
        float4* cv4 = (float4*)cov16;
        int hb = b >> 4, q = b & 15;
        int idx0 = hb * 256 + tid;               // float4 index in a row: [0, 4096)
        float4 s = {0.f, 0.f, 0.f, 0.f};
        #pragma unroll
        for (int n = q * 8; n < q * 8 + 8; ++n) {
            float4 v = ap4[n * (H_LEN / 4) + idx0];
            s.x += v.x; s.y += v.y; s.z += v.z; s.w += v.w;
            op4[n * (H_LEN / 4) + idx0] = v;
        }
        cv4[q * (H_LEN / 4) + idx0] = s;
    } else if (b < 384) {
        int lane = tid & 63;
        int a = (b - 256) * 4 + (tid >> 6);
        const float* row = mlp_dec_w + a * DUNITS;
        float s = 0.f;
        #pragma unroll
        for (int t = 0; t < DUNITS / 64; ++t) s += row[lane + 64 * t] * dec_z[lane + 64 * t];
        #pragma unroll
        for (int off = 32; off > 0; off >>= 1) s += __shfl_xor(s, off, 64);
        if (lane == 0) dz[a] = s;
    } else {
        out_c[tid] = 0.f;
        out_c[tid + 256] = 0.f;
    }
}

// ---------------------------------------------------------------------------
// K2: conv + score + per-block softmax partials + UNNORMALIZED context partial
// (flash-attention style). 512 blocks x 32 h.
__global__ __launch_bounds__(256, 2) void k_score(const float* __restrict__ cov16,
                                                  const float* __restrict__ cw,
                                                  const float* __restrict__ pre,
                                                  const float* __restrict__ mask,
                                                  const float* __restrict__ dz,
                                                  const float* __restrict__ watt,
                                                  const float* __restrict__ gv,
                                                  const float* __restrict__ gb,
                                                  const float* __restrict__ enc,
                                                  float* __restrict__ vbuf,
                                                  float* __restrict__ pm,
                                                  float* __restrict__ ps,
                                                  float* __restrict__ pcb) {
    __shared__ float cov_s[32 + 2 * PAD];   // 232
    __shared__ float mask_s[32];
    __shared__ float pc[8][NCH][32];        // partial conv per tap-eighth (race-free)
    __shared__ float cf[NCH][32];           // final conv
    __shared__ float vt[32];                // scores
    __shared__ float wt[32];                // exp(v - M_b)

    int tid = threadIdx.x, b = blockIdx.x;
    int h0 = b * 32;
    int lane = tid & 63, wv = tid >> 6;
    int a0 = lane * 4;

    // stage LDS: cov window (sum the 16 n-partials) + mask
    for (int i = tid; i < 32 + 2 * PAD; i += 256) {
        int g = h0 - PAD + i;
        float s = 0.f;
        if (g >= 0 && g < H_LEN) {
            #pragma unroll
            for (int q = 0; q < NCOVP; ++q) s += cov16[q * H_LEN + g];
        }
        cov_s[i] = s;
    }
    if (tid < 32) mask_s[tid] = mask[h0 + tid];

    // preload ALL pre fragments for this wave's 8 h (64 VGPRs in flight);
    // conv compute below covers the latency.
    const float4* pre4 = (const float4*)pre;
    int hbase = h0 + wv * 8;
    float4 P[16];
    #pragma unroll
    for (int j = 0; j < 8; ++j) {
        P[2 * j]     = pre4[(hbase + j) * 128 + lane];
        P[2 * j + 1] = pre4[(hbase + j) * 128 + 64 + lane];
    }

    // per-lane weights in registers
    float Wr[8][NCH], dzr[8], gvr[8];
    #pragma unroll
    for (int i = 0; i < 8; ++i) {
        int a = (i < 4) ? (a0 + i) : (a0 + 256 + (i - 4));
        dzr[i] = dz[a];
        gvr[i] = gv[a];
        #pragma unroll
        for (int c = 0; c < NCH; ++c) Wr[i][c] = watt[a * NCH + c];
    }
    float bias = gb[0];
    __syncthreads();

    // conv: 8 tap-groups (q = tid>>5), h = tid&31; k-index wave-uniform -> s_load
    {
        int h = tid & 31, q = tid >> 5;            // q in [0,8)
        int k0 = (q * KFILT) / 8, k1 = ((q + 1) * KFILT) / 8;
        float acc[NCH];
        #pragma unroll
        for (int c = 0; c < NCH; ++c) acc[c] = 0.f;
        for (int k = k0; k < k1; ++k) {
            float s = cov_s[h + k];
            #pragma unroll
            for (int c = 0; c < NCH; ++c) acc[c] += s * cw[c * KFILT + k];
        }
        #pragma unroll
        for (int c = 0; c < NCH; ++c) pc[q][c][h] = acc[c];   // distinct slot per q
    }
    __syncthreads();
    for (int i = tid; i < NCH * 32; i += 256) {
        int c = i >> 5, h = i & 31;
        float s = 0.f;
        #pragma unroll
        for (int q = 0; q < 8; ++q) s += pc[q][c][h];
        cf[c][h] = s;
    }
    __syncthreads();

    // score: wave wv handles h in [8*wv, 8*wv+8)
    #pragma unroll
    for (int j = 0; j < 8; ++j) {
        int hh = wv * 8 + j;
        float ch[NCH];
        #pragma unroll
        for (int c = 0; c < NCH; ++c) ch[c] = cf[c][hh];   // broadcast
        float4 c0 = P[2 * j], c1 = P[2 * j + 1];
        float pv[8] = {c0.x, c0.y, c0.z, c0.w, c1.x, c1.y, c1.z, c1.w};
        float eacc = 0.f;
        #pragma unroll
        for (int i = 0; i < 8; ++i) {
            float x = pv[i] + dzr[i];
            #pragma unroll
            for (int c = 0; c < NCH; ++c) x += ch[c] * Wr[i][c];
            x = fminf(fmaxf(x, -15.f), 15.f);
            float z = __expf(2.f * x);                      // tanh via exp + rcp
            float t = (z - 1.f) * __builtin_amdgcn_rcpf(z + 1.f);
            eacc += t * gvr[i];
        }
        #pragma unroll
        for (int off = 32; off > 0; off >>= 1) eacc += __shfl_xor(eacc, off, 64);
        if (lane == 0) {
            float v = 2.f * (eacc + bias + mask_s[hh]);
            vt[hh] = v;
            vbuf[h0 + hh] = v;
        }
    }
    __syncthreads();

    // wave 0: block softmax partials M_b, s_b; stage wt[h] = exp(v - M_b)
    if (wv == 0) {
        float v = (lane < 32) ? vt[lane] : -1e30f;
        float m = v;
        #pragma unroll
        for (int off = 32; off > 0; off >>= 1) m = fmaxf(m, __shfl_xor(m, off, 64));
        float ev = (lane < 32) ? __expf(v - m) : 0.f;
        if (lane < 32) wt[lane] = ev;
        float s = ev;
        #pragma unroll
        for (int off = 32; off > 0; off >>= 1) s += __shfl_xor(s, off, 64);
        if (lane == 0) { pm[b] = m; ps[b] = s; }
    }
    __syncthreads();

    // unnormalized context partial: thread t owns a = {2t, 2t+1}.
    // Full unroll + two independent accumulators -> loads batched, FMA chain split.
    const float2* enc2 = (const float2*)enc;
    float2 acc0 = {0.f, 0.f}, acc1 = {0.f, 0.f};
    #pragma unroll
    for (int h = 0; h < 32; h += 2) {
        float w0 = wt[h], w1 = wt[h + 1];
        float2 e0 = enc2[(h0 + h) * 256 + tid];
        float2 e1 = enc2[(h0 + h + 1) * 256 + tid];
        acc0.x += w0 * e0.x; acc0.y += w0 * e0.y;
        acc1.x += w1 * e1.x; acc1.y += w1 * e1.y;
    }
    float2 acc = {acc0.x + acc1.x, acc0.y + acc1.y};
    ((float2*)pcb)[b * 256 + tid] = acc;
}

// ---------------------------------------------------------------------------
// K3: finalize. 256 blocks x 256 thr. Redundant merge of 512 (m,s) partials
// (2 KB, L2-hot); block b writes w for 64 h; reduces pcb rows {2b,2b+1} into
// out_c with rescale, via atomics (256 adds/address).
__global__ __launch_bounds__(256) void k_final(const float* __restrict__ vbuf,
                                               const float* __restrict__ pm,
                                               const float* __restrict__ ps,
                                               const float* __restrict__ pcb,
                                               float* __restrict__ out_w,
                                               float* __restrict__ out_c) {
    __shared__ float redA[4], redB[4];
    int tid = threadIdx.x, b = blockIdx.x;
    int lane = tid & 63, wv = tid >> 6;

    float m0 = pm[tid], m1 = pm[tid + 256];
    float s0 = ps[tid], s1 = ps[tid + 256];
    float m = fmaxf(m0, m1);
    #pragma unroll
    for (int off = 32; off > 0; off >>= 1) m = fmaxf(m, __shfl_xor(m, off, 64));
    if (lane == 0) redA[wv] = m;
    __syncthreads();
    float M = fmaxf(fmaxf(redA[0], redA[1]), fmaxf(redA[2], redA[3]));
    float s = s0 * __expf(m0 - M) + s1 * __expf(m1 - M);
    #pragma unroll
    for (int off = 32; off > 0; off >>= 1) s += __shfl_xor(s, off, 64);
    if (lane == 0) redB[wv] = s;
    __syncthreads();
    float S = redB[0] + redB[1] + redB[2] + redB[3];
    float rinv = 1.f / S;

    // w output: 64 h per block
    if (tid < 64) {
        int h = b * 64 + tid;
        out_w[h] = __expf(vbuf[h] - M) * rinv;
    }

    // context reduction: rows 2b, 2b+1 of pcb
    int r0 = 2 * b, r1 = 2 * b + 1;
    float sc0 = __expf(pm[r0] - M) * rinv;
    float sc1 = __expf(pm[r1] - M) * rinv;
    float v0 = pcb[r0 * EPROJS + tid] * sc0 + pcb[r1 * EPROJS + tid] * sc1;
    float v1 = pcb[r0 * EPROJS + tid + 256] * sc0 + pcb[r1 * EPROJS + tid + 256] * sc1;
    atomicAdd(&out_c[tid], v0);
    atomicAdd(&out_c[tid + 256], v1);
}

// ---------------------------------------------------------------------------
extern "C" void kernel_launch(void* const* d_in, const int* in_sizes, int n_in,
                              void* d_out, int out_size, void* d_ws, size_t ws_size,
                              hipStream_t stream) {
    const float* dec_z      = (const float*)d_in[0];
    const float* att_prev   = (const float*)d_in[1];
    const float* pre        = (const float*)d_in[2];
    const float* enc_h      = (const float*)d_in[3];
    const float* mask       = (const float*)d_in[4];
    const float* loc_conv_w = (const float*)d_in[5];
    const float* mlp_att_w  = (const float*)d_in[6];
    const float* mlp_dec_w  = (const float*)d_in[7];
    const float* gvec_w     = (const float*)d_in[8];
    const float* gvec_b     = (const float*)d_in[9];

    float* out_c    = (float*)d_out;                  // [512]
    float* out_prev = out_c + EPROJS;                 // [128*16384]
    float* out_w    = out_prev + N_PREV * H_LEN;      // [16384]

    float* ws    = (float*)d_ws;
    float* cov16 = ws;                                // 16*16384
    float* dz    = cov16 + NCOVP * H_LEN;             // 512
    float* vb    = dz + ATT_DIM;                      // 16384
    float* pm    = vb + H_LEN;                        // 512
    float* ps    = pm + NB_SCORE;                     // 512
    float* pcb   = ps + NB_SCORE;                     // 512*512

    k_prep<<<385, 256, 0, stream>>>(att_prev, mlp_dec_w, dec_z, out_prev, cov16, dz, out_c);
    k_score<<<NB_SCORE, 256, 0, stream>>>(cov16, loc_conv_w, pre, mask, dz, mlp_att_w,
                                          gvec_w, gvec_b, enc_h, vb, pm, ps, pcb);
    k_final<<<NB_FIN, 256, 0, stream>>>(vb, pm, ps, pcb, out_w, out_c);
}